// Round 11
// baseline (4887.100 us; speedup 1.0000x reference)
//
#include <hip/hip_runtime.h>
#include <math.h>

#define NN 100000
#define NE 1600000
#define DD 64
#define NL 4
#define NH 4
#define NC 16
#define DIN 192
#define SLOPE 0.2f
#define EB 128
#define XSTR 200
#define LOG2E 1.44269504088896340736f

typedef __bf16 bf8 __attribute__((ext_vector_type(8)));
typedef __bf16 bf4 __attribute__((ext_vector_type(4)));
typedef __bf16 bf2 __attribute__((ext_vector_type(2)));
typedef float f32x4 __attribute__((ext_vector_type(4)));

__device__ __forceinline__ f32x4 MFMA(bf8 a, bf8 b, f32x4 c) {
  return __builtin_amdgcn_mfma_f32_16x16x32_bf16(a, b, c, 0, 0, 0);
}

// ---------------- weight packing: single bf16 plane, 1KB tiles ----------------
__global__ void k_pack_w1(const float* __restrict__ W1, __bf16* __restrict__ WH) {
  int gidx = blockIdx.x * 256 + threadIdx.x;
  if (gidx >= 4 * 4608) return;
  int lyr = gidx / 4608, rem = gidx % 4608;
  int lane = rem & 63, ts = rem >> 6;
  int s = ts % 6, t = ts / 6;
  const float* Wl = W1 + (size_t)lyr * DIN * DIN;
  size_t base = (size_t)lyr * 36864 + ((size_t)(t * 6 + s) * 64 + lane) * 8;
  int k0 = s * 32 + (lane >> 4) * 8, n = t * 16 + (lane & 15);
#pragma unroll
  for (int j = 0; j < 8; ++j)
    WH[base + j] = (__bf16)Wl[(size_t)(k0 + j) * DIN + n];
}

__global__ void k_pack_w2(const float* __restrict__ W2, __bf16* __restrict__ WH) {
  int gidx = blockIdx.x * 256 + threadIdx.x;
  if (gidx >= 4 * 1536) return;
  int lyr = gidx / 1536, rem = gidx % 1536;
  int lane = rem & 63, ts = rem >> 6;
  int s = ts % 6, t = ts / 6;
  const float* Wl = W2 + (size_t)lyr * DIN * DD;
  size_t base = (size_t)lyr * 12288 + ((size_t)(t * 6 + s) * 64 + lane) * 8;
  int k0 = s * 32 + (lane >> 4) * 8, n = t * 16 + (lane & 15);
#pragma unroll
  for (int j = 0; j < 8; ++j)
    WH[base + j] = (__bf16)Wl[(size_t)(k0 + j) * DD + n];
}

// ---------------- CSR build ----------------
__global__ void k_zero(int* __restrict__ deg) {
  int i = blockIdx.x * 256 + threadIdx.x;
  if (i < NN) deg[i] = 0;
}

__global__ void k_hist(const int* __restrict__ dst, int* __restrict__ deg) {
  int e = blockIdx.x * 256 + threadIdx.x;
  if (e < NE) atomicAdd(&deg[dst[e]], 1);
}

__global__ void k_scan1(const int* __restrict__ deg, int* __restrict__ offs,
                        int* __restrict__ bsum) {
  __shared__ int sh[256];
  int t = threadIdx.x, b = blockIdx.x;
  int i0 = b * 1024 + t * 4;
  int d0 = (i0 + 0 < NN) ? deg[i0 + 0] : 0;
  int d1 = (i0 + 1 < NN) ? deg[i0 + 1] : 0;
  int d2 = (i0 + 2 < NN) ? deg[i0 + 2] : 0;
  int d3 = (i0 + 3 < NN) ? deg[i0 + 3] : 0;
  int s4 = d0 + d1 + d2 + d3;
  sh[t] = s4;
  __syncthreads();
  int p = 0;
#pragma unroll
  for (int off = 1; off < 256; off <<= 1) {
    int v = (t >= off) ? sh[t - off] : 0;
    __syncthreads();
    sh[t] += v;
    __syncthreads();
  }
  p = sh[t] - s4;
  if (t == 255) bsum[b] = sh[255];
  if (i0 + 0 < NN) offs[i0 + 0] = p;
  if (i0 + 1 < NN) offs[i0 + 1] = p + d0;
  if (i0 + 2 < NN) offs[i0 + 2] = p + d0 + d1;
  if (i0 + 3 < NN) offs[i0 + 3] = p + d0 + d1 + d2;
}

__global__ void k_scan2(int* __restrict__ bsum, int* __restrict__ boff,
                        int* __restrict__ offs, int nb) {
  if (threadIdx.x == 0 && blockIdx.x == 0) {
    int run = 0;
    for (int k = 0; k < nb; ++k) { boff[k] = run; run += bsum[k]; }
    offs[NN] = NE;
  }
}

__global__ void k_scan3(int* __restrict__ offs, const int* __restrict__ boff,
                        int* __restrict__ cursor) {
  int i = blockIdx.x * 256 + threadIdx.x;
  if (i < NN) {
    int v = offs[i] + boff[i >> 10];
    offs[i] = v;
    cursor[i] = v;
  }
}

__global__ void k_scatter(const int* __restrict__ src, const int* __restrict__ dst,
                          int* __restrict__ cursor, int* __restrict__ csr_src,
                          int* __restrict__ posmap) {
  int e = blockIdx.x * 256 + threadIdx.x;
  if (e >= NE) return;
  int pos = atomicAdd(&cursor[dst[e]], 1);
  csr_src[pos] = src[e];
  posmap[e] = pos;
}

// ---------------- upfront precomputes ----------------
__global__ void k_v_all(const float* __restrict__ ew_all, const float* __restrict__ ae_all,
                        float* __restrict__ vbuf) {
  int l = blockIdx.x;
  const float* ew = ew_all + (size_t)l * DD * DD;
  const float* ae = ae_all + (size_t)l * NH * NC;
  int d = threadIdx.x >> 2, h = threadIdx.x & 3;
  float s = 0.f;
#pragma unroll
  for (int c = 0; c < NC; ++c) s = fmaf(ew[d * DD + h * NC + c], ae[h * NC + c], s);
  vbuf[l * 256 + d * NH + h] = s;
}

// ef copy (fp32, d_out) + raw pe0 = ef.v0 scattered to araw[posmap]
__global__ void k_init_ef_p1(const float* __restrict__ edge_feats,
                             const float* __restrict__ v0,
                             const int* __restrict__ posmap,
                             float* __restrict__ ef, float* __restrict__ araw) {
  int e = blockIdx.x * 4 + (threadIdx.x >> 6);
  int d = threadIdx.x & 63;
  float x = edge_feats[(size_t)e * DD + d];
  ef[(size_t)e * DD + d] = x;
  float4 v4 = ((const float4*)v0)[d];
  float p0 = x * v4.x, p1 = x * v4.y, p2 = x * v4.z, p3 = x * v4.w;
#pragma unroll
  for (int off = 32; off >= 1; off >>= 1) {
    p0 += __shfl_xor(p0, off, 64);
    p1 += __shfl_xor(p1, off, 64);
    p2 += __shfl_xor(p2, off, 64);
    p3 += __shfl_xor(p3, off, 64);
  }
  if (d < 4) {
    float pe = (d == 0) ? p0 : (d == 1) ? p1 : (d == 2) ? p2 : p3;
    araw[(size_t)posmap[e] * NH + d] = pe;
  }
}

// ---------------- conv path ----------------
__global__ void k_xh(const float* __restrict__ nf, const float* __restrict__ W,
                     const float* __restrict__ as_, const float* __restrict__ ad_,
                     __bf16* __restrict__ xh16, float* __restrict__ asrc,
                     float* __restrict__ adst) {
  int t = blockIdx.x * 4 + (threadIdx.x >> 6);
  int d = threadIdx.x & 63;
  if (t >= NN) return;
  const float* x = nf + (size_t)t * DD;
  float acc = 0.f;
#pragma unroll
  for (int k = 0; k < DD; ++k) acc = fmaf(x[k], W[k * DD + d], acc);
  xh16[(size_t)t * DD + d] = (__bf16)acc;
  int h = d >> 4, c = d & 15;
  float ps = acc * as_[h * NC + c];
  float pd = acc * ad_[h * NC + c];
#pragma unroll
  for (int off = 8; off >= 1; off >>= 1) {
    ps += __shfl_xor(ps, off, 64);
    pd += __shfl_xor(pd, off, 64);
  }
  if (c == 0) { asrc[t * NH + h] = ps; adst[t * NH + h] = pd; }
}

// pass1 (layers 1..3): raw pe = ef.v only, scattered to CSR position
__global__ void k_pass1raw(const float* __restrict__ ef, const float* __restrict__ v,
                           const int* __restrict__ posmap, float* __restrict__ araw) {
  int e = blockIdx.x * 64 + (threadIdx.x >> 2);
  int part = threadIdx.x & 3;
  if (e >= NE) return;
  float ph0 = 0.f, ph1 = 0.f, ph2 = 0.f, ph3 = 0.f;
  const float4* ep = (const float4*)(ef + (size_t)e * DD + part * 16);
  const float4* v4 = (const float4*)v;
#pragma unroll
  for (int c4 = 0; c4 < 4; ++c4) {
    float4 x = ep[c4];
    int d0 = part * 16 + c4 * 4;
    float4 va = v4[d0], vb = v4[d0 + 1], vc = v4[d0 + 2], vd = v4[d0 + 3];
    ph0 = fmaf(x.x, va.x, fmaf(x.y, vb.x, fmaf(x.z, vc.x, fmaf(x.w, vd.x, ph0))));
    ph1 = fmaf(x.x, va.y, fmaf(x.y, vb.y, fmaf(x.z, vc.y, fmaf(x.w, vd.y, ph1))));
    ph2 = fmaf(x.x, va.z, fmaf(x.y, vb.z, fmaf(x.z, vc.z, fmaf(x.w, vd.z, ph2))));
    ph3 = fmaf(x.x, va.w, fmaf(x.y, vb.w, fmaf(x.z, vc.w, fmaf(x.w, vd.w, ph3))));
  }
#pragma unroll
  for (int off = 1; off <= 2; off <<= 1) {
    ph0 += __shfl_xor(ph0, off, 64);
    ph1 += __shfl_xor(ph1, off, 64);
    ph2 += __shfl_xor(ph2, off, 64);
    ph3 += __shfl_xor(ph3, off, 64);
  }
  float pe = (part == 0) ? ph0 : (part == 1) ? ph1 : (part == 2) ? ph2 : ph3;
  araw[(size_t)posmap[e] * NH + part] = pe;
}

// gather: araw holds RAW pe; alpha = leaky(asrc[s]+adst[t]+pe)*LOG2E inline
__global__ __launch_bounds__(256) void k_gather2(
    const __bf16* __restrict__ xh16, const float* __restrict__ araw,
    const int* __restrict__ csr_src, const int* __restrict__ offs,
    const float* __restrict__ asrc, const float* __restrict__ adst,
    const float* __restrict__ cb, const float* __restrict__ g,
    const float* __restrict__ bln, float* __restrict__ nf,
    __bf16* __restrict__ nf16) {
  int t = blockIdx.x * 4 + (threadIdx.x >> 6);
  int d = threadIdx.x & 63;
  if (t >= NN) return;
  int h = d >> 4;
  int o0 = offs[t], o1 = offs[t + 1];
  int deg = o1 - o0;
  float4 ad4 = ((const float4*)adst)[t];

  float m0 = -INFINITY, m1 = -INFINITY, m2 = -INFINITY, m3 = -INFINITY;
  for (int base = 0; base < deg; base += 64) {
    int j = base + d;
    if (j < deg) {
      int pos = o0 + j;
      float4 pe = *(const float4*)(araw + (size_t)pos * NH);
      int sp = csr_src[pos];
      float4 as4 = ((const float4*)asrc)[sp];
      float a0 = as4.x + ad4.x + pe.x; a0 = ((a0 > 0.f) ? a0 : SLOPE * a0) * LOG2E;
      float a1 = as4.y + ad4.y + pe.y; a1 = ((a1 > 0.f) ? a1 : SLOPE * a1) * LOG2E;
      float a2 = as4.z + ad4.z + pe.z; a2 = ((a2 > 0.f) ? a2 : SLOPE * a2) * LOG2E;
      float a3 = as4.w + ad4.w + pe.w; a3 = ((a3 > 0.f) ? a3 : SLOPE * a3) * LOG2E;
      m0 = fmaxf(m0, a0); m1 = fmaxf(m1, a1);
      m2 = fmaxf(m2, a2); m3 = fmaxf(m3, a3);
    }
  }
#pragma unroll
  for (int off = 32; off >= 1; off >>= 1) {
    m0 = fmaxf(m0, __shfl_xor(m0, off, 64));
    m1 = fmaxf(m1, __shfl_xor(m1, off, 64));
    m2 = fmaxf(m2, __shfl_xor(m2, off, 64));
    m3 = fmaxf(m3, __shfl_xor(m3, off, 64));
  }
  float adh = (h == 0) ? ad4.x : (h == 1) ? ad4.y : (h == 2) ? ad4.z : ad4.w;
  float ash = asrc[t * NH + h];
  float sh = ash + adh;
  sh = ((sh > 0.f) ? sh : SLOPE * sh) * LOG2E;
  float mh = (h == 0) ? m0 : (h == 1) ? m1 : (h == 2) ? m2 : m3;
  mh = fmaxf(mh, sh);

  float acc = 0.f, wsum = 0.f;
  int j = 0;
  for (; j + 1 < deg; j += 2) {
    int pos0 = o0 + j, pos1 = o0 + j + 1;
    int sp0 = csr_src[pos0], sp1 = csr_src[pos1];
    float ar0 = asrc[sp0 * NH + h] + adh + araw[(size_t)pos0 * NH + h];
    float ar1 = asrc[sp1 * NH + h] + adh + araw[(size_t)pos1 * NH + h];
    ar0 = ((ar0 > 0.f) ? ar0 : SLOPE * ar0) * LOG2E;
    ar1 = ((ar1 > 0.f) ? ar1 : SLOPE * ar1) * LOG2E;
    float w0 = exp2f(ar0 - mh), w1 = exp2f(ar1 - mh);
    acc = fmaf(w0, (float)xh16[(size_t)sp0 * DD + d], acc);
    acc = fmaf(w1, (float)xh16[(size_t)sp1 * DD + d], acc);
    wsum += w0 + w1;
  }
  if (j < deg) {
    int pos = o0 + j;
    int sp = csr_src[pos];
    float ar = asrc[sp * NH + h] + adh + araw[(size_t)pos * NH + h];
    ar = ((ar > 0.f) ? ar : SLOPE * ar) * LOG2E;
    float w = exp2f(ar - mh);
    acc = fmaf(w, (float)xh16[(size_t)sp * DD + d], acc);
    wsum += w;
  }
  float wself = exp2f(sh - mh);
  acc = fmaf(wself, (float)xh16[(size_t)t * DD + d], acc);
  wsum += wself;

  float val = acc / (wsum + 1e-16f) + cb[d];
  float m = val;
#pragma unroll
  for (int off = 32; off >= 1; off >>= 1) m += __shfl_xor(m, off, 64);
  m *= (1.f / 64.f);
  float c = val - m;
  float q = c * c;
#pragma unroll
  for (int off = 32; off >= 1; off >>= 1) q += __shfl_xor(q, off, 64);
  float rstd = 1.f / sqrtf(q * (1.f / 64.f) + 1e-5f);
  float y = c * rstd * g[d] + bln[d];
  y = fmaxf(y, 0.f);
  float out = y + nf[(size_t)t * DD + d];
  nf[(size_t)t * DD + d] = out;
  nf16[(size_t)t * DD + d] = (__bf16)out;
}

// ---------------- edge MLP v8: v6 + residual snapshot from LDS ---------------
// 128 edges/block, 8 waves (2 rg x 4 cg). Residual read from staged XH (bf16)
// before barrier 1 -> no fp32 ef re-read from global.
__global__ __launch_bounds__(512, 6) void k_edge_mlp8(
    const __bf16* __restrict__ nf16, float* __restrict__ ef,
    const int* __restrict__ src, const int* __restrict__ dst,
    const __bf16* __restrict__ W1H, const float* __restrict__ b1,
    const float* __restrict__ g, const float* __restrict__ bg,
    const __bf16* __restrict__ W2H, const float* __restrict__ b2) {
  __shared__ __bf16 XH[EB * XSTR];   // 51200 B: X during GEMM1, H after
  __shared__ __bf16 Pb[EB * 8];      // 2048 B: LN partials; slot 0 -> (mean,rstd)
  int tid = threadIdx.x;
  int e0 = blockIdx.x * EB;

  // stage X: thread owns (row = tid>>2, part p = tid&3)
  {
    int row = tid >> 2, p = tid & 3;
    int se = src[e0 + row], de = dst[e0 + row];
    const bf8* psrc = (const bf8*)(nf16 + (size_t)se * DD + p * 16);
    *(bf8*)&XH[row * XSTR + p * 16]     = psrc[0];
    *(bf8*)&XH[row * XSTR + p * 16 + 8] = psrc[1];
    const bf8* pdst = (const bf8*)(nf16 + (size_t)de * DD + p * 16);
    *(bf8*)&XH[row * XSTR + 64 + p * 16]     = pdst[0];
    *(bf8*)&XH[row * XSTR + 64 + p * 16 + 8] = pdst[1];
    const float4* pef = (const float4*)(ef + (size_t)(e0 + row) * DD + p * 16);
#pragma unroll
    for (int k = 0; k < 4; ++k) {
      float4 v = pef[k];
      bf4 hv;
      hv[0] = (__bf16)v.x; hv[1] = (__bf16)v.y;
      hv[2] = (__bf16)v.z; hv[3] = (__bf16)v.w;
      *(bf4*)&XH[row * XSTR + 128 + p * 16 + k * 4] = hv;
    }
  }
  __syncthreads();

  int w = tid >> 6, l = tid & 63;
  int rg = w >> 2, cg = w & 3;
  int gq = l >> 4, i = l & 15;
  int col = cg * 16 + i;

  f32x4 acc[4][3];
#pragma unroll
  for (int rt = 0; rt < 4; ++rt)
#pragma unroll
    for (int t = 0; t < 3; ++t) acc[rt][t] = (f32x4){0.f, 0.f, 0.f, 0.f};

  // GEMM1: no barriers; B-tiles from global (L2-hot)
#pragma unroll
  for (int s = 0; s < 6; ++s) {
    bf8 a[4];
#pragma unroll
    for (int rt = 0; rt < 4; ++rt)
      a[rt] = *(const bf8*)&XH[(rg * 64 + rt * 16 + i) * XSTR + s * 32 + gq * 8];
#pragma unroll
    for (int t = 0; t < 3; ++t) {
      bf8 bh = *(const bf8*)(W1H + ((size_t)((cg * 3 + t) * 6 + s) * 64 + l) * 8);
#pragma unroll
      for (int rt = 0; rt < 4; ++rt) acc[rt][t] = MFMA(a[rt], bh, acc[rt][t]);
    }
  }

  // residual snapshot (XH ef-region stable until H overwrite after barrier 2)
  float res[4][4];
#pragma unroll
  for (int rt = 0; rt < 4; ++rt)
#pragma unroll
    for (int r = 0; r < 4; ++r)
      res[rt][r] = (float)XH[(rg * 64 + rt * 16 + gq * 4 + r) * XSTR + 128 + col];

  float b1v[3], gv[3], bgv[3];
#pragma unroll
  for (int t = 0; t < 3; ++t) {
    int n = cg * 48 + t * 16 + i;
    b1v[t] = b1[n]; gv[t] = g[n]; bgv[t] = bg[n];
  }
#pragma unroll
  for (int rt = 0; rt < 4; ++rt)
#pragma unroll
    for (int t = 0; t < 3; ++t)
#pragma unroll
      for (int r = 0; r < 4; ++r) acc[rt][t][r] += b1v[t];

#pragma unroll
  for (int rt = 0; rt < 4; ++rt)
#pragma unroll
    for (int r = 0; r < 4; ++r) {
      float sm = 0.f, sq = 0.f;
#pragma unroll
      for (int t = 0; t < 3; ++t) { float x = acc[rt][t][r]; sm += x; sq = fmaf(x, x, sq); }
#pragma unroll
      for (int off = 1; off <= 8; off <<= 1) {
        sm += __shfl_xor(sm, off, 64);
        sq += __shfl_xor(sq, off, 64);
      }
      if (i == 0) {
        int row = rg * 64 + rt * 16 + gq * 4 + r;
        bf2 pr; pr[0] = (__bf16)sm; pr[1] = (__bf16)sq;
        *(bf2*)&Pb[row * 8 + cg * 2] = pr;
      }
    }
  __syncthreads();   // barrier 1: partials ready; all X reads (incl. res) done

  if (tid < EB) {
    bf8 pv = *(const bf8*)&Pb[tid * 8];
    float sm = (float)pv[0] + (float)pv[2] + (float)pv[4] + (float)pv[6];
    float sq = (float)pv[1] + (float)pv[3] + (float)pv[5] + (float)pv[7];
    float mean = sm * (1.f / (float)DIN);
    float var = sq * (1.f / (float)DIN) - mean * mean;
    float rstd = 1.f / sqrtf(var + 1e-5f);
    bf2 mv; mv[0] = (__bf16)mean; mv[1] = (__bf16)rstd;
    *(bf2*)&Pb[tid * 8] = mv;
  }
  __syncthreads();   // barrier 2: (mean,rstd) ready

#pragma unroll
  for (int rt = 0; rt < 4; ++rt)
#pragma unroll
    for (int r = 0; r < 4; ++r) {
      int row = rg * 64 + rt * 16 + gq * 4 + r;
      bf2 mv = *(const bf2*)&Pb[row * 8];
      float mean = (float)mv[0], rstd = (float)mv[1];
#pragma unroll
      for (int t = 0; t < 3; ++t) {
        float y = (acc[rt][t][r] - mean) * rstd * gv[t] + bgv[t];
        y = fmaxf(y, 0.f);
        XH[row * XSTR + cg * 48 + t * 16 + i] = (__bf16)y;
      }
    }
  __syncthreads();   // barrier 3: H fully published

  // GEMM2
  f32x4 acc2[4];
#pragma unroll
  for (int rt = 0; rt < 4; ++rt) acc2[rt] = (f32x4){0.f, 0.f, 0.f, 0.f};

#pragma unroll
  for (int s = 0; s < 6; ++s) {
    bf8 a2[4];
#pragma unroll
    for (int rt = 0; rt < 4; ++rt)
      a2[rt] = *(const bf8*)&XH[(rg * 64 + rt * 16 + i) * XSTR + s * 32 + gq * 8];
    bf8 bh = *(const bf8*)(W2H + ((size_t)(cg * 6 + s) * 64 + l) * 8);
#pragma unroll
    for (int rt = 0; rt < 4; ++rt) acc2[rt] = MFMA(a2[rt], bh, acc2[rt]);
  }

  float b2v = b2[col];
#pragma unroll
  for (int rt = 0; rt < 4; ++rt)
#pragma unroll
    for (int r = 0; r < 4; ++r) {
      int row = rg * 64 + rt * 16 + gq * 4 + r;
      ef[(size_t)(e0 + row) * DD + col] = acc2[rt][r] + b2v + res[rt][r];
    }
}

extern "C" void kernel_launch(void* const* d_in, const int* in_sizes, int n_in,
                              void* d_out, int out_size, void* d_ws, size_t ws_size,
                              hipStream_t stream) {
  const float* node_feats = (const float*)d_in[0];
  const float* edge_feats = (const float*)d_in[1];
  const int*   edge_index = (const int*)d_in[2];
  const float* conv_w  = (const float*)d_in[3];
  const float* att_src = (const float*)d_in[4];
  const float* att_dst = (const float*)d_in[5];
  const float* edge_w  = (const float*)d_in[6];
  const float* att_edge= (const float*)d_in[7];
  const float* conv_b  = (const float*)d_in[8];
  const float* ln_g    = (const float*)d_in[9];
  const float* ln_b    = (const float*)d_in[10];
  const float* up1_w   = (const float*)d_in[11];
  const float* up1_b   = (const float*)d_in[12];
  const float* up_ln_g = (const float*)d_in[13];
  const float* up_ln_b = (const float*)d_in[14];
  const float* up2_w   = (const float*)d_in[15];
  const float* up2_b   = (const float*)d_in[16];

  const int* src = edge_index;
  const int* dst = edge_index + NE;

  float* nf = (float*)d_out;
  float* ef = nf + (size_t)NN * DD;

  float* w = (float*)d_ws;
  __bf16* xh16 = (__bf16*)w; w += (size_t)NN * DD / 2;
  __bf16* nf16 = (__bf16*)w; w += (size_t)NN * DD / 2;
  float* asrc  = w; w += (size_t)NN * NH;
  float* adst  = w; w += (size_t)NN * NH;
  float* araw  = w; w += (size_t)NE * NH;          // RAW pe per edge (CSR order)
  float* vbuf  = w; w += 4 * 256;
  __bf16* W1H  = (__bf16*)w; w += (size_t)4 * 36864 / 2;
  __bf16* W2H  = (__bf16*)w; w += (size_t)4 * 12288 / 2;
  int* deg     = (int*)w; w += NN;
  int* offs    = (int*)w; w += NN + 1;
  int* cursor  = (int*)w; w += NN;
  int* bsum    = (int*)w; w += 128;
  int* boff    = (int*)w; w += 128;
  int* csr_src = (int*)w; w += NE;
  int* posmap  = (int*)w; w += NE;

  hipMemcpyAsync(nf, node_feats, (size_t)NN * DD * sizeof(float),
                 hipMemcpyDeviceToDevice, stream);

  k_pack_w1<<<72, 256, 0, stream>>>(up1_w, W1H);
  k_pack_w2<<<24, 256, 0, stream>>>(up2_w, W2H);

  const int nb = (NN + 1023) / 1024;
  k_zero<<<(NN + 255) / 256, 256, 0, stream>>>(deg);
  k_hist<<<(NE + 255) / 256, 256, 0, stream>>>(dst, deg);
  k_scan1<<<nb, 256, 0, stream>>>(deg, offs, bsum);
  k_scan2<<<1, 64, 0, stream>>>(bsum, boff, offs, nb);
  k_scan3<<<(NN + 255) / 256, 256, 0, stream>>>(offs, boff, cursor);
  k_scatter<<<(NE + 255) / 256, 256, 0, stream>>>(src, dst, cursor, csr_src, posmap);

  k_v_all<<<4, 256, 0, stream>>>(edge_w, att_edge, vbuf);
  // ef copy + layer-0 pe in one pass over edge_feats
  k_init_ef_p1<<<NE / 4, 256, 0, stream>>>(edge_feats, vbuf, posmap, ef, araw);

  for (int l = 0; l < NL; ++l) {
    k_xh<<<NN / 4, 256, 0, stream>>>(nf, conv_w + (size_t)l * DD * DD,
                                     att_src + (size_t)l * NH * NC,
                                     att_dst + (size_t)l * NH * NC, xh16, asrc, adst);
    if (l > 0)
      k_pass1raw<<<NE / 64, 256, 0, stream>>>(ef, vbuf + (size_t)l * 256, posmap, araw);
    k_gather2<<<NN / 4, 256, 0, stream>>>(xh16, araw, csr_src, offs, asrc, adst,
                                          conv_b + (size_t)l * DD,
                                          ln_g + (size_t)l * DD,
                                          ln_b + (size_t)l * DD, nf, nf16);
    k_edge_mlp8<<<NE / EB, 512, 0, stream>>>(
        nf16, ef, src, dst,
        W1H + (size_t)l * 36864, up1_b + (size_t)l * DIN,
        up_ln_g + (size_t)l * DIN, up_ln_b + (size_t)l * DIN,
        W2H + (size_t)l * 12288, up2_b + (size_t)l * DD);
  }
}

// Round 12
// 3931.783 us; speedup vs baseline: 1.2430x; 1.2430x over previous
//
#include <hip/hip_runtime.h>
#include <math.h>

#define NN 100000
#define NE 1600000
#define DD 64
#define NL 4
#define NH 4
#define NC 16
#define DIN 192
#define SLOPE 0.2f
#define EB 128
#define XSTR 200
#define FSTR 66
#define LOG2E 1.44269504088896340736f

typedef __bf16 bf8 __attribute__((ext_vector_type(8)));
typedef __bf16 bf4 __attribute__((ext_vector_type(4)));
typedef __bf16 bf2 __attribute__((ext_vector_type(2)));
typedef float f32x4 __attribute__((ext_vector_type(4)));

__device__ __forceinline__ f32x4 MFMA(bf8 a, bf8 b, f32x4 c) {
  return __builtin_amdgcn_mfma_f32_16x16x32_bf16(a, b, c, 0, 0, 0);
}

// ---------------- weight packing: single bf16 plane, 1KB tiles ----------------
__global__ void k_pack_w1(const float* __restrict__ W1, __bf16* __restrict__ WH) {
  int gidx = blockIdx.x * 256 + threadIdx.x;
  if (gidx >= 4 * 4608) return;
  int lyr = gidx / 4608, rem = gidx % 4608;
  int lane = rem & 63, ts = rem >> 6;
  int s = ts % 6, t = ts / 6;
  const float* Wl = W1 + (size_t)lyr * DIN * DIN;
  size_t base = (size_t)lyr * 36864 + ((size_t)(t * 6 + s) * 64 + lane) * 8;
  int k0 = s * 32 + (lane >> 4) * 8, n = t * 16 + (lane & 15);
#pragma unroll
  for (int j = 0; j < 8; ++j)
    WH[base + j] = (__bf16)Wl[(size_t)(k0 + j) * DIN + n];
}

__global__ void k_pack_w2(const float* __restrict__ W2, __bf16* __restrict__ WH) {
  int gidx = blockIdx.x * 256 + threadIdx.x;
  if (gidx >= 4 * 1536) return;
  int lyr = gidx / 1536, rem = gidx % 1536;
  int lane = rem & 63, ts = rem >> 6;
  int s = ts % 6, t = ts / 6;
  const float* Wl = W2 + (size_t)lyr * DIN * DD;
  size_t base = (size_t)lyr * 12288 + ((size_t)(t * 6 + s) * 64 + lane) * 8;
  int k0 = s * 32 + (lane >> 4) * 8, n = t * 16 + (lane & 15);
#pragma unroll
  for (int j = 0; j < 8; ++j)
    WH[base + j] = (__bf16)Wl[(size_t)(k0 + j) * DD + n];
}

// ---------------- CSR build ----------------
__global__ void k_zero(int* __restrict__ deg) {
  int i = blockIdx.x * 256 + threadIdx.x;
  if (i < NN) deg[i] = 0;
}

__global__ void k_hist(const int* __restrict__ dst, int* __restrict__ deg) {
  int e = blockIdx.x * 256 + threadIdx.x;
  if (e < NE) atomicAdd(&deg[dst[e]], 1);
}

__global__ void k_scan1(const int* __restrict__ deg, int* __restrict__ offs,
                        int* __restrict__ bsum) {
  __shared__ int sh[256];
  int t = threadIdx.x, b = blockIdx.x;
  int i0 = b * 1024 + t * 4;
  int d0 = (i0 + 0 < NN) ? deg[i0 + 0] : 0;
  int d1 = (i0 + 1 < NN) ? deg[i0 + 1] : 0;
  int d2 = (i0 + 2 < NN) ? deg[i0 + 2] : 0;
  int d3 = (i0 + 3 < NN) ? deg[i0 + 3] : 0;
  int s4 = d0 + d1 + d2 + d3;
  sh[t] = s4;
  __syncthreads();
  int p = 0;
#pragma unroll
  for (int off = 1; off < 256; off <<= 1) {
    int v = (t >= off) ? sh[t - off] : 0;
    __syncthreads();
    sh[t] += v;
    __syncthreads();
  }
  p = sh[t] - s4;
  if (t == 255) bsum[b] = sh[255];
  if (i0 + 0 < NN) offs[i0 + 0] = p;
  if (i0 + 1 < NN) offs[i0 + 1] = p + d0;
  if (i0 + 2 < NN) offs[i0 + 2] = p + d0 + d1;
  if (i0 + 3 < NN) offs[i0 + 3] = p + d0 + d1 + d2;
}

__global__ void k_scan2(int* __restrict__ bsum, int* __restrict__ boff,
                        int* __restrict__ offs, int nb) {
  if (threadIdx.x == 0 && blockIdx.x == 0) {
    int run = 0;
    for (int k = 0; k < nb; ++k) { boff[k] = run; run += bsum[k]; }
    offs[NN] = NE;
  }
}

__global__ void k_scan3(int* __restrict__ offs, const int* __restrict__ boff,
                        int* __restrict__ cursor) {
  int i = blockIdx.x * 256 + threadIdx.x;
  if (i < NN) {
    int v = offs[i] + boff[i >> 10];
    offs[i] = v;
    cursor[i] = v;
  }
}

__global__ void k_scatter(const int* __restrict__ src, const int* __restrict__ dst,
                          int* __restrict__ cursor, int* __restrict__ csr_src,
                          int* __restrict__ posmap) {
  int e = blockIdx.x * 256 + threadIdx.x;
  if (e >= NE) return;
  int pos = atomicAdd(&cursor[dst[e]], 1);
  csr_src[pos] = src[e];
  posmap[e] = pos;
}

// ---------------- upfront precomputes ----------------
__global__ void k_v_all(const float* __restrict__ ew_all, const float* __restrict__ ae_all,
                        float* __restrict__ vbuf) {
  int l = blockIdx.x;
  const float* ew = ew_all + (size_t)l * DD * DD;
  const float* ae = ae_all + (size_t)l * NH * NC;
  int d = threadIdx.x >> 2, h = threadIdx.x & 3;
  float s = 0.f;
#pragma unroll
  for (int c = 0; c < NC; ++c) s = fmaf(ew[d * DD + h * NC + c], ae[h * NC + c], s);
  vbuf[l * 256 + d * NH + h] = s;
}

__global__ void k_init_nf(const float* __restrict__ node_feats, float* __restrict__ nf) {
  int i = blockIdx.x * 256 + threadIdx.x;
  if (i < NN * DD) nf[i] = node_feats[i];
}

// ---------------- conv path ----------------
__global__ void k_xh(const float* __restrict__ nf, const float* __restrict__ W,
                     const float* __restrict__ as_, const float* __restrict__ ad_,
                     __bf16* __restrict__ xh16, float* __restrict__ asrc,
                     float* __restrict__ adst) {
  int t = blockIdx.x * 4 + (threadIdx.x >> 6);
  int d = threadIdx.x & 63;
  if (t >= NN) return;
  const float* x = nf + (size_t)t * DD;
  float acc = 0.f;
#pragma unroll
  for (int k = 0; k < DD; ++k) acc = fmaf(x[k], W[k * DD + d], acc);
  xh16[(size_t)t * DD + d] = (__bf16)acc;
  int h = d >> 4, c = d & 15;
  float ps = acc * as_[h * NC + c];
  float pd = acc * ad_[h * NC + c];
#pragma unroll
  for (int off = 8; off >= 1; off >>= 1) {
    ps += __shfl_xor(ps, off, 64);
    pd += __shfl_xor(pd, off, 64);
  }
  if (c == 0) { asrc[t * NH + h] = ps; adst[t * NH + h] = pd; }
}

// pass1 layer 0: reads edge_feats fp32, writes ef16 AND finished alpha
__global__ void k_pass1f(const float* __restrict__ edge_feats,
                         const int* __restrict__ src, const int* __restrict__ dst,
                         const float* __restrict__ v,
                         const float* __restrict__ asrc, const float* __restrict__ adst,
                         const int* __restrict__ posmap,
                         __bf16* __restrict__ ef16, float* __restrict__ araw) {
  int e = blockIdx.x * 64 + (threadIdx.x >> 2);
  int part = threadIdx.x & 3;
  if (e >= NE) return;
  int s = src[e], t = dst[e];
  float ph0 = 0.f, ph1 = 0.f, ph2 = 0.f, ph3 = 0.f;
  const float4* ep = (const float4*)(edge_feats + (size_t)e * DD + part * 16);
  const float4* v4 = (const float4*)v;
  bf4 outv[4];
#pragma unroll
  for (int c4 = 0; c4 < 4; ++c4) {
    float4 x = ep[c4];
    outv[c4][0] = (__bf16)x.x; outv[c4][1] = (__bf16)x.y;
    outv[c4][2] = (__bf16)x.z; outv[c4][3] = (__bf16)x.w;
    int d0 = part * 16 + c4 * 4;
    float4 va = v4[d0], vb = v4[d0 + 1], vc = v4[d0 + 2], vd = v4[d0 + 3];
    ph0 = fmaf(x.x, va.x, fmaf(x.y, vb.x, fmaf(x.z, vc.x, fmaf(x.w, vd.x, ph0))));
    ph1 = fmaf(x.x, va.y, fmaf(x.y, vb.y, fmaf(x.z, vc.y, fmaf(x.w, vd.y, ph1))));
    ph2 = fmaf(x.x, va.z, fmaf(x.y, vb.z, fmaf(x.z, vc.z, fmaf(x.w, vd.z, ph2))));
    ph3 = fmaf(x.x, va.w, fmaf(x.y, vb.w, fmaf(x.z, vc.w, fmaf(x.w, vd.w, ph3))));
  }
  // 32 B contiguous bf16 store per lane; 4 lanes cover the 128 B row-line
  *(bf8*)&ef16[(size_t)e * DD + part * 16] =
      (bf8){outv[0][0], outv[0][1], outv[0][2], outv[0][3],
            outv[1][0], outv[1][1], outv[1][2], outv[1][3]};
  *(bf8*)&ef16[(size_t)e * DD + part * 16 + 8] =
      (bf8){outv[2][0], outv[2][1], outv[2][2], outv[2][3],
            outv[3][0], outv[3][1], outv[3][2], outv[3][3]};
#pragma unroll
  for (int off = 1; off <= 2; off <<= 1) {
    ph0 += __shfl_xor(ph0, off, 64);
    ph1 += __shfl_xor(ph1, off, 64);
    ph2 += __shfl_xor(ph2, off, 64);
    ph3 += __shfl_xor(ph3, off, 64);
  }
  float pe = (part == 0) ? ph0 : (part == 1) ? ph1 : (part == 2) ? ph2 : ph3;
  float a = asrc[s * NH + part] + adst[t * NH + part] + pe;
  a = (a > 0.f) ? a : SLOPE * a;
  araw[(size_t)posmap[e] * NH + part] = a * LOG2E;
}

// pass1 layers 1..3: reads ef16
__global__ void k_pass1b(const __bf16* __restrict__ ef16,
                         const int* __restrict__ src, const int* __restrict__ dst,
                         const float* __restrict__ v,
                         const float* __restrict__ asrc, const float* __restrict__ adst,
                         const int* __restrict__ posmap, float* __restrict__ araw) {
  int e = blockIdx.x * 64 + (threadIdx.x >> 2);
  int part = threadIdx.x & 3;
  if (e >= NE) return;
  int s = src[e], t = dst[e];
  float ph0 = 0.f, ph1 = 0.f, ph2 = 0.f, ph3 = 0.f;
  const bf8* ep = (const bf8*)(ef16 + (size_t)e * DD + part * 16);
  bf8 x0 = ep[0], x1 = ep[1];
  const float4* v4 = (const float4*)v;
#pragma unroll
  for (int m = 0; m < 16; ++m) {
    float xv = (m < 8) ? (float)x0[m] : (float)x1[m - 8];
    float4 vn = v4[part * 16 + m];
    ph0 = fmaf(xv, vn.x, ph0);
    ph1 = fmaf(xv, vn.y, ph1);
    ph2 = fmaf(xv, vn.z, ph2);
    ph3 = fmaf(xv, vn.w, ph3);
  }
#pragma unroll
  for (int off = 1; off <= 2; off <<= 1) {
    ph0 += __shfl_xor(ph0, off, 64);
    ph1 += __shfl_xor(ph1, off, 64);
    ph2 += __shfl_xor(ph2, off, 64);
    ph3 += __shfl_xor(ph3, off, 64);
  }
  float pe = (part == 0) ? ph0 : (part == 1) ? ph1 : (part == 2) ? ph2 : ph3;
  float a = asrc[s * NH + part] + adst[t * NH + part] + pe;
  a = (a > 0.f) ? a : SLOPE * a;
  araw[(size_t)posmap[e] * NH + part] = a * LOG2E;
}

// gather (R9 form): araw holds finished alpha (leaky'd, *LOG2E)
__global__ __launch_bounds__(256) void k_gather(
    const __bf16* __restrict__ xh16, const float* __restrict__ araw,
    const int* __restrict__ csr_src, const int* __restrict__ offs,
    const float* __restrict__ asrc, const float* __restrict__ adst,
    const float* __restrict__ cb, const float* __restrict__ g,
    const float* __restrict__ bln, float* __restrict__ nf,
    __bf16* __restrict__ nf16) {
  int t = blockIdx.x * 4 + (threadIdx.x >> 6);
  int d = threadIdx.x & 63;
  if (t >= NN) return;
  int h = d >> 4;
  int o0 = offs[t], o1 = offs[t + 1];
  int deg = o1 - o0;

  float m0 = -INFINITY, m1 = -INFINITY, m2 = -INFINITY, m3 = -INFINITY;
  for (int base = 0; base < deg; base += 64) {
    int j = base + d;
    if (j < deg) {
      float4 a = *(const float4*)(araw + (size_t)(o0 + j) * NH);
      m0 = fmaxf(m0, a.x); m1 = fmaxf(m1, a.y);
      m2 = fmaxf(m2, a.z); m3 = fmaxf(m3, a.w);
    }
  }
#pragma unroll
  for (int off = 32; off >= 1; off >>= 1) {
    m0 = fmaxf(m0, __shfl_xor(m0, off, 64));
    m1 = fmaxf(m1, __shfl_xor(m1, off, 64));
    m2 = fmaxf(m2, __shfl_xor(m2, off, 64));
    m3 = fmaxf(m3, __shfl_xor(m3, off, 64));
  }
  float sh = asrc[t * NH + h] + adst[t * NH + h];
  sh = ((sh > 0.f) ? sh : SLOPE * sh) * LOG2E;
  float mh = (h == 0) ? m0 : (h == 1) ? m1 : (h == 2) ? m2 : m3;
  mh = fmaxf(mh, sh);

  float acc = 0.f, wsum = 0.f;
  int j = 0;
  for (; j + 1 < deg; j += 2) {
    int sp0 = csr_src[o0 + j], sp1 = csr_src[o0 + j + 1];
    float ar0 = araw[(size_t)(o0 + j) * NH + h];
    float ar1 = araw[(size_t)(o0 + j + 1) * NH + h];
    float w0 = exp2f(ar0 - mh), w1 = exp2f(ar1 - mh);
    acc = fmaf(w0, (float)xh16[(size_t)sp0 * DD + d], acc);
    acc = fmaf(w1, (float)xh16[(size_t)sp1 * DD + d], acc);
    wsum += w0 + w1;
  }
  if (j < deg) {
    int sp = csr_src[o0 + j];
    float ar = araw[(size_t)(o0 + j) * NH + h];
    float w = exp2f(ar - mh);
    acc = fmaf(w, (float)xh16[(size_t)sp * DD + d], acc);
    wsum += w;
  }
  float wself = exp2f(sh - mh);
  acc = fmaf(wself, (float)xh16[(size_t)t * DD + d], acc);
  wsum += wself;

  float val = acc / (wsum + 1e-16f) + cb[d];
  float m = val;
#pragma unroll
  for (int off = 32; off >= 1; off >>= 1) m += __shfl_xor(m, off, 64);
  m *= (1.f / 64.f);
  float c = val - m;
  float q = c * c;
#pragma unroll
  for (int off = 32; off >= 1; off >>= 1) q += __shfl_xor(q, off, 64);
  float rstd = 1.f / sqrtf(q * (1.f / 64.f) + 1e-5f);
  float y = c * rstd * g[d] + bln[d];
  y = fmaxf(y, 0.f);
  float out = y + nf[(size_t)t * DD + d];
  nf[(size_t)t * DD + d] = out;
  nf16[(size_t)t * DD + d] = (__bf16)out;
}

// ---------------- edge MLP v9: ef16 carry + LDS output funnel ----------------
// 128 edges/block, 8 waves. Stage all-bf16 (no cvt). Residual from LDS snapshot.
// Output funneled through LDS (f32, stride 66) -> full-line coalesced stores:
// l<3 writes ef16 (128 B/row lines), l=3 writes fp32 ef in d_out.
__global__ __launch_bounds__(512, 6) void k_edge_mlp9(
    const __bf16* __restrict__ nf16, __bf16* __restrict__ ef16,
    float* __restrict__ efout,
    const int* __restrict__ src, const int* __restrict__ dst,
    const __bf16* __restrict__ W1H, const float* __restrict__ b1,
    const float* __restrict__ g, const float* __restrict__ bg,
    const __bf16* __restrict__ W2H, const float* __restrict__ b2, int last) {
  __shared__ __bf16 XH[EB * XSTR];   // 51200 B: X | H | f32 output funnel
  __shared__ __bf16 Pb[EB * 8];      // 2048 B: LN partials; slot 0 -> (mean,rstd)
  int tid = threadIdx.x;
  int e0 = blockIdx.x * EB;
  float* XF = (float*)XH;            // funnel view (needs 128*66*4 = 33792 B)

  // stage X: thread owns (row = tid>>2, part p = tid&3); all bf16 copies
  {
    int row = tid >> 2, p = tid & 3;
    int se = src[e0 + row], de = dst[e0 + row];
    const bf8* psrc = (const bf8*)(nf16 + (size_t)se * DD + p * 16);
    *(bf8*)&XH[row * XSTR + p * 16]     = psrc[0];
    *(bf8*)&XH[row * XSTR + p * 16 + 8] = psrc[1];
    const bf8* pdst = (const bf8*)(nf16 + (size_t)de * DD + p * 16);
    *(bf8*)&XH[row * XSTR + 64 + p * 16]     = pdst[0];
    *(bf8*)&XH[row * XSTR + 64 + p * 16 + 8] = pdst[1];
    const bf8* pef = (const bf8*)(ef16 + (size_t)(e0 + row) * DD + p * 16);
    *(bf8*)&XH[row * XSTR + 128 + p * 16]     = pef[0];
    *(bf8*)&XH[row * XSTR + 128 + p * 16 + 8] = pef[1];
  }
  __syncthreads();

  int w = tid >> 6, l = tid & 63;
  int rg = w >> 2, cg = w & 3;
  int gq = l >> 4, i = l & 15;
  int col = cg * 16 + i;

  f32x4 acc[4][3];
#pragma unroll
  for (int rt = 0; rt < 4; ++rt)
#pragma unroll
    for (int t = 0; t < 3; ++t) acc[rt][t] = (f32x4){0.f, 0.f, 0.f, 0.f};

  // GEMM1: no barriers; B-tiles from global (L2-hot)
#pragma unroll
  for (int s = 0; s < 6; ++s) {
    bf8 a[4];
#pragma unroll
    for (int rt = 0; rt < 4; ++rt)
      a[rt] = *(const bf8*)&XH[(rg * 64 + rt * 16 + i) * XSTR + s * 32 + gq * 8];
#pragma unroll
    for (int t = 0; t < 3; ++t) {
      bf8 bh = *(const bf8*)(W1H + ((size_t)((cg * 3 + t) * 6 + s) * 64 + l) * 8);
#pragma unroll
      for (int rt = 0; rt < 4; ++rt) acc[rt][t] = MFMA(a[rt], bh, acc[rt][t]);
    }
  }

  // residual snapshot from staged ef (stable until H overwrite after barrier 2)
  float res[4][4];
#pragma unroll
  for (int rt = 0; rt < 4; ++rt)
#pragma unroll
    for (int r = 0; r < 4; ++r)
      res[rt][r] = (float)XH[(rg * 64 + rt * 16 + gq * 4 + r) * XSTR + 128 + col];

  float b1v[3], gv[3], bgv[3];
#pragma unroll
  for (int t = 0; t < 3; ++t) {
    int n = cg * 48 + t * 16 + i;
    b1v[t] = b1[n]; gv[t] = g[n]; bgv[t] = bg[n];
  }
#pragma unroll
  for (int rt = 0; rt < 4; ++rt)
#pragma unroll
    for (int t = 0; t < 3; ++t)
#pragma unroll
      for (int r = 0; r < 4; ++r) acc[rt][t][r] += b1v[t];

#pragma unroll
  for (int rt = 0; rt < 4; ++rt)
#pragma unroll
    for (int r = 0; r < 4; ++r) {
      float sm = 0.f, sq = 0.f;
#pragma unroll
      for (int t = 0; t < 3; ++t) { float x = acc[rt][t][r]; sm += x; sq = fmaf(x, x, sq); }
#pragma unroll
      for (int off = 1; off <= 8; off <<= 1) {
        sm += __shfl_xor(sm, off, 64);
        sq += __shfl_xor(sq, off, 64);
      }
      if (i == 0) {
        int row = rg * 64 + rt * 16 + gq * 4 + r;
        bf2 pr; pr[0] = (__bf16)sm; pr[1] = (__bf16)sq;
        *(bf2*)&Pb[row * 8 + cg * 2] = pr;
      }
    }
  __syncthreads();   // barrier 1: partials ready; all X reads (incl. res) done

  if (tid < EB) {
    bf8 pv = *(const bf8*)&Pb[tid * 8];
    float sm = (float)pv[0] + (float)pv[2] + (float)pv[4] + (float)pv[6];
    float sq = (float)pv[1] + (float)pv[3] + (float)pv[5] + (float)pv[7];
    float mean = sm * (1.f / (float)DIN);
    float var = sq * (1.f / (float)DIN) - mean * mean;
    float rstd = 1.f / sqrtf(var + 1e-5f);
    bf2 mv; mv[0] = (__bf16)mean; mv[1] = (__bf16)rstd;
    *(bf2*)&Pb[tid * 8] = mv;
  }
  __syncthreads();   // barrier 2: (mean,rstd) ready

#pragma unroll
  for (int rt = 0; rt < 4; ++rt)
#pragma unroll
    for (int r = 0; r < 4; ++r) {
      int row = rg * 64 + rt * 16 + gq * 4 + r;
      bf2 mv = *(const bf2*)&Pb[row * 8];
      float mean = (float)mv[0], rstd = (float)mv[1];
#pragma unroll
      for (int t = 0; t < 3; ++t) {
        float y = (acc[rt][t][r] - mean) * rstd * gv[t] + bgv[t];
        y = fmaxf(y, 0.f);
        XH[row * XSTR + cg * 48 + t * 16 + i] = (__bf16)y;
      }
    }
  __syncthreads();   // barrier 3: H fully published

  // GEMM2
  f32x4 acc2[4];
#pragma unroll
  for (int rt = 0; rt < 4; ++rt) acc2[rt] = (f32x4){0.f, 0.f, 0.f, 0.f};

#pragma unroll
  for (int s = 0; s < 6; ++s) {
    bf8 a2[4];
#pragma unroll
    for (int rt = 0; rt < 4; ++rt)
      a2[rt] = *(const bf8*)&XH[(rg * 64 + rt * 16 + i) * XSTR + s * 32 + gq * 8];
    bf8 bh = *(const bf8*)(W2H + ((size_t)(cg * 6 + s) * 64 + l) * 8);
#pragma unroll
    for (int rt = 0; rt < 4; ++rt) acc2[rt] = MFMA(a2[rt], bh, acc2[rt]);
  }
  __syncthreads();   // barrier 4: all H reads done; XH free for funnel

  float b2v = b2[col];
#pragma unroll
  for (int rt = 0; rt < 4; ++rt)
#pragma unroll
    for (int r = 0; r < 4; ++r) {
      int row = rg * 64 + rt * 16 + gq * 4 + r;
      XF[row * FSTR + col] = acc2[rt][r] + b2v + res[rt][r];
    }
  __syncthreads();   // barrier 5: funnel filled

  // full-line coalesced output: thread owns (row = tid>>2, q = tid&3)
  {
    int row = tid >> 2, q = tid & 3;
    const float* fr = &XF[row * FSTR + q * 16];
    if (last) {
      float* op = efout + (size_t)(e0 + row) * DD + q * 16;
#pragma unroll
      for (int k = 0; k < 4; ++k)
        *(float4*)(op + k * 4) = *(const float4*)(fr + k * 4);
    } else {
      bf8 o0, o1;
#pragma unroll
      for (int k = 0; k < 8; ++k) { o0[k] = (__bf16)fr[k]; o1[k] = (__bf16)fr[k + 8]; }
      __bf16* op = ef16 + (size_t)(e0 + row) * DD + q * 16;
      *(bf8*)op = o0;
      *(bf8*)(op + 8) = o1;
    }
  }
}

extern "C" void kernel_launch(void* const* d_in, const int* in_sizes, int n_in,
                              void* d_out, int out_size, void* d_ws, size_t ws_size,
                              hipStream_t stream) {
  const float* node_feats = (const float*)d_in[0];
  const float* edge_feats = (const float*)d_in[1];
  const int*   edge_index = (const int*)d_in[2];
  const float* conv_w  = (const float*)d_in[3];
  const float* att_src = (const float*)d_in[4];
  const float* att_dst = (const float*)d_in[5];
  const float* edge_w  = (const float*)d_in[6];
  const float* att_edge= (const float*)d_in[7];
  const float* conv_b  = (const float*)d_in[8];
  const float* ln_g    = (const float*)d_in[9];
  const float* ln_b    = (const float*)d_in[10];
  const float* up1_w   = (const float*)d_in[11];
  const float* up1_b   = (const float*)d_in[12];
  const float* up_ln_g = (const float*)d_in[13];
  const float* up_ln_b = (const float*)d_in[14];
  const float* up2_w   = (const float*)d_in[15];
  const float* up2_b   = (const float*)d_in[16];

  const int* src = edge_index;
  const int* dst = edge_index + NE;

  float* nf = (float*)d_out;
  float* efout = nf + (size_t)NN * DD;

  float* w = (float*)d_ws;
  __bf16* xh16 = (__bf16*)w; w += (size_t)NN * DD / 2;
  __bf16* nf16 = (__bf16*)w; w += (size_t)NN * DD / 2;
  __bf16* ef16 = (__bf16*)w; w += (size_t)NE * DD / 2;
  float* asrc  = w; w += (size_t)NN * NH;
  float* adst  = w; w += (size_t)NN * NH;
  float* araw  = w; w += (size_t)NE * NH;
  float* vbuf  = w; w += 4 * 256;
  __bf16* W1H  = (__bf16*)w; w += (size_t)4 * 36864 / 2;
  __bf16* W2H  = (__bf16*)w; w += (size_t)4 * 12288 / 2;
  int* deg     = (int*)w; w += NN;
  int* offs    = (int*)w; w += NN + 1;
  int* cursor  = (int*)w; w += NN;
  int* bsum    = (int*)w; w += 128;
  int* boff    = (int*)w; w += 128;
  int* csr_src = (int*)w; w += NE;
  int* posmap  = (int*)w; w += NE;

  k_init_nf<<<(NN * DD + 255) / 256, 256, 0, stream>>>(node_feats, nf);
  k_pack_w1<<<72, 256, 0, stream>>>(up1_w, W1H);
  k_pack_w2<<<24, 256, 0, stream>>>(up2_w, W2H);

  const int nb = (NN + 1023) / 1024;
  k_zero<<<(NN + 255) / 256, 256, 0, stream>>>(deg);
  k_hist<<<(NE + 255) / 256, 256, 0, stream>>>(dst, deg);
  k_scan1<<<nb, 256, 0, stream>>>(deg, offs, bsum);
  k_scan2<<<1, 64, 0, stream>>>(bsum, boff, offs, nb);
  k_scan3<<<(NN + 255) / 256, 256, 0, stream>>>(offs, boff, cursor);
  k_scatter<<<(NE + 255) / 256, 256, 0, stream>>>(src, dst, cursor, csr_src, posmap);

  k_v_all<<<4, 256, 0, stream>>>(edge_w, att_edge, vbuf);

  for (int l = 0; l < NL; ++l) {
    int last = (l == NL - 1) ? 1 : 0;
    k_xh<<<NN / 4, 256, 0, stream>>>(nf, conv_w + (size_t)l * DD * DD,
                                     att_src + (size_t)l * NH * NC,
                                     att_dst + (size_t)l * NH * NC, xh16, asrc, adst);
    if (l == 0)
      k_pass1f<<<NE / 64, 256, 0, stream>>>(edge_feats, src, dst, vbuf,
                                            asrc, adst, posmap, ef16, araw);
    else
      k_pass1b<<<NE / 64, 256, 0, stream>>>(ef16, src, dst,
                                            vbuf + (size_t)l * 256,
                                            asrc, adst, posmap, araw);
    k_gather<<<NN / 4, 256, 0, stream>>>(xh16, araw, csr_src, offs, asrc, adst,
                                         conv_b + (size_t)l * DD,
                                         ln_g + (size_t)l * DD,
                                         ln_b + (size_t)l * DD, nf, nf16);
    k_edge_mlp9<<<NE / EB, 512, 0, stream>>>(
        nf16, ef16, efout, src, dst,
        W1H + (size_t)l * 36864, up1_b + (size_t)l * DIN,
        up_ln_g + (size_t)l * DIN, up_ln_b + (size_t)l * DIN,
        W2H + (size_t)l * 12288, up2_b + (size_t)l * DD, last);
  }
}

// Round 13
// 3379.118 us; speedup vs baseline: 1.4463x; 1.1636x over previous
//
#include <hip/hip_runtime.h>
#include <math.h>

#define NN 100000
#define NE 1600000
#define DD 64
#define NL 4
#define NH 4
#define NC 16
#define DIN 192
#define SLOPE 0.2f
#define EB 128
#define XSTR 200
#define FSTR 66
#define LOG2E 1.44269504088896340736f

typedef __bf16 bf8 __attribute__((ext_vector_type(8)));
typedef __bf16 bf4 __attribute__((ext_vector_type(4)));
typedef __bf16 bf2 __attribute__((ext_vector_type(2)));
typedef float f32x4 __attribute__((ext_vector_type(4)));

__device__ __forceinline__ f32x4 MFMA(bf8 a, bf8 b, f32x4 c) {
  return __builtin_amdgcn_mfma_f32_16x16x32_bf16(a, b, c, 0, 0, 0);
}

// ---------------- weight packing: single bf16 plane, 1KB tiles ----------------
__global__ void k_pack_w1(const float* __restrict__ W1, __bf16* __restrict__ WH) {
  int gidx = blockIdx.x * 256 + threadIdx.x;
  if (gidx >= 4 * 4608) return;
  int lyr = gidx / 4608, rem = gidx % 4608;
  int lane = rem & 63, ts = rem >> 6;
  int s = ts % 6, t = ts / 6;
  const float* Wl = W1 + (size_t)lyr * DIN * DIN;
  size_t base = (size_t)lyr * 36864 + ((size_t)(t * 6 + s) * 64 + lane) * 8;
  int k0 = s * 32 + (lane >> 4) * 8, n = t * 16 + (lane & 15);
#pragma unroll
  for (int j = 0; j < 8; ++j)
    WH[base + j] = (__bf16)Wl[(size_t)(k0 + j) * DIN + n];
}

__global__ void k_pack_w2(const float* __restrict__ W2, __bf16* __restrict__ WH) {
  int gidx = blockIdx.x * 256 + threadIdx.x;
  if (gidx >= 4 * 1536) return;
  int lyr = gidx / 1536, rem = gidx % 1536;
  int lane = rem & 63, ts = rem >> 6;
  int s = ts % 6, t = ts / 6;
  const float* Wl = W2 + (size_t)lyr * DIN * DD;
  size_t base = (size_t)lyr * 12288 + ((size_t)(t * 6 + s) * 64 + lane) * 8;
  int k0 = s * 32 + (lane >> 4) * 8, n = t * 16 + (lane & 15);
#pragma unroll
  for (int j = 0; j < 8; ++j)
    WH[base + j] = (__bf16)Wl[(size_t)(k0 + j) * DD + n];
}

// ---------------- CSR build ----------------
__global__ void k_zero(int* __restrict__ deg) {
  int i = blockIdx.x * 256 + threadIdx.x;
  if (i < NN) deg[i] = 0;
}

__global__ void k_hist(const int* __restrict__ dst, int* __restrict__ deg) {
  int e = blockIdx.x * 256 + threadIdx.x;
  if (e < NE) atomicAdd(&deg[dst[e]], 1);
}

__global__ void k_scan1(const int* __restrict__ deg, int* __restrict__ offs,
                        int* __restrict__ bsum) {
  __shared__ int sh[256];
  int t = threadIdx.x, b = blockIdx.x;
  int i0 = b * 1024 + t * 4;
  int d0 = (i0 + 0 < NN) ? deg[i0 + 0] : 0;
  int d1 = (i0 + 1 < NN) ? deg[i0 + 1] : 0;
  int d2 = (i0 + 2 < NN) ? deg[i0 + 2] : 0;
  int d3 = (i0 + 3 < NN) ? deg[i0 + 3] : 0;
  int s4 = d0 + d1 + d2 + d3;
  sh[t] = s4;
  __syncthreads();
  int p = 0;
#pragma unroll
  for (int off = 1; off < 256; off <<= 1) {
    int v = (t >= off) ? sh[t - off] : 0;
    __syncthreads();
    sh[t] += v;
    __syncthreads();
  }
  p = sh[t] - s4;
  if (t == 255) bsum[b] = sh[255];
  if (i0 + 0 < NN) offs[i0 + 0] = p;
  if (i0 + 1 < NN) offs[i0 + 1] = p + d0;
  if (i0 + 2 < NN) offs[i0 + 2] = p + d0 + d1;
  if (i0 + 3 < NN) offs[i0 + 3] = p + d0 + d1 + d2;
}

__global__ void k_scan2(int* __restrict__ bsum, int* __restrict__ boff,
                        int* __restrict__ offs, int nb) {
  if (threadIdx.x == 0 && blockIdx.x == 0) {
    int run = 0;
    for (int k = 0; k < nb; ++k) { boff[k] = run; run += bsum[k]; }
    offs[NN] = NE;
  }
}

__global__ void k_scan3(int* __restrict__ offs, const int* __restrict__ boff,
                        int* __restrict__ cursor) {
  int i = blockIdx.x * 256 + threadIdx.x;
  if (i < NN) {
    int v = offs[i] + boff[i >> 10];
    offs[i] = v;
    cursor[i] = v;
  }
}

__global__ void k_scatter(const int* __restrict__ src, const int* __restrict__ dst,
                          int* __restrict__ cursor, int* __restrict__ csr_src,
                          int* __restrict__ posmap) {
  int e = blockIdx.x * 256 + threadIdx.x;
  if (e >= NE) return;
  int pos = atomicAdd(&cursor[dst[e]], 1);
  csr_src[pos] = src[e];
  posmap[e] = pos;
}

// ---------------- upfront precomputes ----------------
__global__ void k_v_all(const float* __restrict__ ew_all, const float* __restrict__ ae_all,
                        float* __restrict__ vbuf) {
  int l = blockIdx.x;
  const float* ew = ew_all + (size_t)l * DD * DD;
  const float* ae = ae_all + (size_t)l * NH * NC;
  int d = threadIdx.x >> 2, h = threadIdx.x & 3;
  float s = 0.f;
#pragma unroll
  for (int c = 0; c < NC; ++c) s = fmaf(ew[d * DD + h * NC + c], ae[h * NC + c], s);
  vbuf[l * 256 + d * NH + h] = s;
}

__global__ void k_init_nf(const float* __restrict__ node_feats, float* __restrict__ nf) {
  int i = blockIdx.x * 256 + threadIdx.x;
  if (i < NN * DD) nf[i] = node_feats[i];
}

// ---------------- conv path ----------------
__global__ void k_xh(const float* __restrict__ nf, const float* __restrict__ W,
                     const float* __restrict__ as_, const float* __restrict__ ad_,
                     __bf16* __restrict__ xh16, float* __restrict__ asrc,
                     float* __restrict__ adst) {
  int t = blockIdx.x * 4 + (threadIdx.x >> 6);
  int d = threadIdx.x & 63;
  if (t >= NN) return;
  const float* x = nf + (size_t)t * DD;
  float acc = 0.f;
#pragma unroll
  for (int k = 0; k < DD; ++k) acc = fmaf(x[k], W[k * DD + d], acc);
  xh16[(size_t)t * DD + d] = (__bf16)acc;
  int h = d >> 4, c = d & 15;
  float ps = acc * as_[h * NC + c];
  float pd = acc * ad_[h * NC + c];
#pragma unroll
  for (int off = 8; off >= 1; off >>= 1) {
    ps += __shfl_xor(ps, off, 64);
    pd += __shfl_xor(pd, off, 64);
  }
  if (c == 0) { asrc[t * NH + h] = ps; adst[t * NH + h] = pd; }
}

// pass1 layer 0: reads edge_feats fp32, writes ef16 AND finished alpha
__global__ void k_pass1f(const float* __restrict__ edge_feats,
                         const int* __restrict__ src, const int* __restrict__ dst,
                         const float* __restrict__ v,
                         const float* __restrict__ asrc, const float* __restrict__ adst,
                         const int* __restrict__ posmap,
                         __bf16* __restrict__ ef16, float* __restrict__ araw) {
  int e = blockIdx.x * 64 + (threadIdx.x >> 2);
  int part = threadIdx.x & 3;
  if (e >= NE) return;
  int s = src[e], t = dst[e];
  float ph0 = 0.f, ph1 = 0.f, ph2 = 0.f, ph3 = 0.f;
  const float4* ep = (const float4*)(edge_feats + (size_t)e * DD + part * 16);
  const float4* v4 = (const float4*)v;
  bf4 outv[4];
#pragma unroll
  for (int c4 = 0; c4 < 4; ++c4) {
    float4 x = ep[c4];
    outv[c4][0] = (__bf16)x.x; outv[c4][1] = (__bf16)x.y;
    outv[c4][2] = (__bf16)x.z; outv[c4][3] = (__bf16)x.w;
    int d0 = part * 16 + c4 * 4;
    float4 va = v4[d0], vb = v4[d0 + 1], vc = v4[d0 + 2], vd = v4[d0 + 3];
    ph0 = fmaf(x.x, va.x, fmaf(x.y, vb.x, fmaf(x.z, vc.x, fmaf(x.w, vd.x, ph0))));
    ph1 = fmaf(x.x, va.y, fmaf(x.y, vb.y, fmaf(x.z, vc.y, fmaf(x.w, vd.y, ph1))));
    ph2 = fmaf(x.x, va.z, fmaf(x.y, vb.z, fmaf(x.z, vc.z, fmaf(x.w, vd.z, ph2))));
    ph3 = fmaf(x.x, va.w, fmaf(x.y, vb.w, fmaf(x.z, vc.w, fmaf(x.w, vd.w, ph3))));
  }
  *(bf8*)&ef16[(size_t)e * DD + part * 16] =
      (bf8){outv[0][0], outv[0][1], outv[0][2], outv[0][3],
            outv[1][0], outv[1][1], outv[1][2], outv[1][3]};
  *(bf8*)&ef16[(size_t)e * DD + part * 16 + 8] =
      (bf8){outv[2][0], outv[2][1], outv[2][2], outv[2][3],
            outv[3][0], outv[3][1], outv[3][2], outv[3][3]};
#pragma unroll
  for (int off = 1; off <= 2; off <<= 1) {
    ph0 += __shfl_xor(ph0, off, 64);
    ph1 += __shfl_xor(ph1, off, 64);
    ph2 += __shfl_xor(ph2, off, 64);
    ph3 += __shfl_xor(ph3, off, 64);
  }
  float pe = (part == 0) ? ph0 : (part == 1) ? ph1 : (part == 2) ? ph2 : ph3;
  float a = asrc[s * NH + part] + adst[t * NH + part] + pe;
  a = (a > 0.f) ? a : SLOPE * a;
  araw[(size_t)posmap[e] * NH + part] = a * LOG2E;
}

// pass1 layers 1..3: reads ef16
__global__ void k_pass1b(const __bf16* __restrict__ ef16,
                         const int* __restrict__ src, const int* __restrict__ dst,
                         const float* __restrict__ v,
                         const float* __restrict__ asrc, const float* __restrict__ adst,
                         const int* __restrict__ posmap, float* __restrict__ araw) {
  int e = blockIdx.x * 64 + (threadIdx.x >> 2);
  int part = threadIdx.x & 3;
  if (e >= NE) return;
  int s = src[e], t = dst[e];
  float ph0 = 0.f, ph1 = 0.f, ph2 = 0.f, ph3 = 0.f;
  const bf8* ep = (const bf8*)(ef16 + (size_t)e * DD + part * 16);
  bf8 x0 = ep[0], x1 = ep[1];
  const float4* v4 = (const float4*)v;
#pragma unroll
  for (int m = 0; m < 16; ++m) {
    float xv = (m < 8) ? (float)x0[m] : (float)x1[m - 8];
    float4 vn = v4[part * 16 + m];
    ph0 = fmaf(xv, vn.x, ph0);
    ph1 = fmaf(xv, vn.y, ph1);
    ph2 = fmaf(xv, vn.z, ph2);
    ph3 = fmaf(xv, vn.w, ph3);
  }
#pragma unroll
  for (int off = 1; off <= 2; off <<= 1) {
    ph0 += __shfl_xor(ph0, off, 64);
    ph1 += __shfl_xor(ph1, off, 64);
    ph2 += __shfl_xor(ph2, off, 64);
    ph3 += __shfl_xor(ph3, off, 64);
  }
  float pe = (part == 0) ? ph0 : (part == 1) ? ph1 : (part == 2) ? ph2 : ph3;
  float a = asrc[s * NH + part] + adst[t * NH + part] + pe;
  a = (a > 0.f) ? a : SLOPE * a;
  araw[(size_t)posmap[e] * NH + part] = a * LOG2E;
}

// gather: araw holds finished alpha (leaky'd, *LOG2E)
__global__ __launch_bounds__(256) void k_gather(
    const __bf16* __restrict__ xh16, const float* __restrict__ araw,
    const int* __restrict__ csr_src, const int* __restrict__ offs,
    const float* __restrict__ asrc, const float* __restrict__ adst,
    const float* __restrict__ cb, const float* __restrict__ g,
    const float* __restrict__ bln, float* __restrict__ nf,
    __bf16* __restrict__ nf16) {
  int t = blockIdx.x * 4 + (threadIdx.x >> 6);
  int d = threadIdx.x & 63;
  if (t >= NN) return;
  int h = d >> 4;
  int o0 = offs[t], o1 = offs[t + 1];
  int deg = o1 - o0;

  float m0 = -INFINITY, m1 = -INFINITY, m2 = -INFINITY, m3 = -INFINITY;
  for (int base = 0; base < deg; base += 64) {
    int j = base + d;
    if (j < deg) {
      float4 a = *(const float4*)(araw + (size_t)(o0 + j) * NH);
      m0 = fmaxf(m0, a.x); m1 = fmaxf(m1, a.y);
      m2 = fmaxf(m2, a.z); m3 = fmaxf(m3, a.w);
    }
  }
#pragma unroll
  for (int off = 32; off >= 1; off >>= 1) {
    m0 = fmaxf(m0, __shfl_xor(m0, off, 64));
    m1 = fmaxf(m1, __shfl_xor(m1, off, 64));
    m2 = fmaxf(m2, __shfl_xor(m2, off, 64));
    m3 = fmaxf(m3, __shfl_xor(m3, off, 64));
  }
  float sh = asrc[t * NH + h] + adst[t * NH + h];
  sh = ((sh > 0.f) ? sh : SLOPE * sh) * LOG2E;
  float mh = (h == 0) ? m0 : (h == 1) ? m1 : (h == 2) ? m2 : m3;
  mh = fmaxf(mh, sh);

  float acc = 0.f, wsum = 0.f;
  int j = 0;
  for (; j + 1 < deg; j += 2) {
    int sp0 = csr_src[o0 + j], sp1 = csr_src[o0 + j + 1];
    float ar0 = araw[(size_t)(o0 + j) * NH + h];
    float ar1 = araw[(size_t)(o0 + j + 1) * NH + h];
    float w0 = exp2f(ar0 - mh), w1 = exp2f(ar1 - mh);
    acc = fmaf(w0, (float)xh16[(size_t)sp0 * DD + d], acc);
    acc = fmaf(w1, (float)xh16[(size_t)sp1 * DD + d], acc);
    wsum += w0 + w1;
  }
  if (j < deg) {
    int sp = csr_src[o0 + j];
    float ar = araw[(size_t)(o0 + j) * NH + h];
    float w = exp2f(ar - mh);
    acc = fmaf(w, (float)xh16[(size_t)sp * DD + d], acc);
    wsum += w;
  }
  float wself = exp2f(sh - mh);
  acc = fmaf(wself, (float)xh16[(size_t)t * DD + d], acc);
  wsum += wself;

  float val = acc / (wsum + 1e-16f) + cb[d];
  float m = val;
#pragma unroll
  for (int off = 32; off >= 1; off >>= 1) m += __shfl_xor(m, off, 64);
  m *= (1.f / 64.f);
  float c = val - m;
  float q = c * c;
#pragma unroll
  for (int off = 32; off >= 1; off >>= 1) q += __shfl_xor(q, off, 64);
  float rstd = 1.f / sqrtf(q * (1.f / 64.f) + 1e-5f);
  float y = c * rstd * g[d] + bln[d];
  y = fmaxf(y, 0.f);
  float out = y + nf[(size_t)t * DD + d];
  nf[(size_t)t * DD + d] = out;
  nf16[(size_t)t * DD + d] = (__bf16)out;
}

// ---------------- edge MLP v10: mlp9 structure, (512,4) = 128-VGPR budget ----
// Fix for R10-R12 regressions: (512,6) made the allocator emit a 40-VGPR
// kernel that spilled the 48-reg accumulator to scratch (1.2 GB HBM writes).
__global__ __launch_bounds__(512, 4) void k_edge_mlp10(
    const __bf16* __restrict__ nf16, __bf16* __restrict__ ef16,
    float* __restrict__ efout,
    const int* __restrict__ src, const int* __restrict__ dst,
    const __bf16* __restrict__ W1H, const float* __restrict__ b1,
    const float* __restrict__ g, const float* __restrict__ bg,
    const __bf16* __restrict__ W2H, const float* __restrict__ b2, int last) {
  __shared__ __bf16 XH[EB * XSTR];   // 51200 B: X | H | f32 output funnel
  __shared__ __bf16 Pb[EB * 8];      // 2048 B: LN partials; slot 0 -> (mean,rstd)
  int tid = threadIdx.x;
  int e0 = blockIdx.x * EB;
  float* XF = (float*)XH;            // funnel view (128*66*4 = 33792 B)

  // stage X: thread owns (row = tid>>2, part p = tid&3); all bf16 copies
  {
    int row = tid >> 2, p = tid & 3;
    int se = src[e0 + row], de = dst[e0 + row];
    const bf8* psrc = (const bf8*)(nf16 + (size_t)se * DD + p * 16);
    *(bf8*)&XH[row * XSTR + p * 16]     = psrc[0];
    *(bf8*)&XH[row * XSTR + p * 16 + 8] = psrc[1];
    const bf8* pdst = (const bf8*)(nf16 + (size_t)de * DD + p * 16);
    *(bf8*)&XH[row * XSTR + 64 + p * 16]     = pdst[0];
    *(bf8*)&XH[row * XSTR + 64 + p * 16 + 8] = pdst[1];
    const bf8* pef = (const bf8*)(ef16 + (size_t)(e0 + row) * DD + p * 16);
    *(bf8*)&XH[row * XSTR + 128 + p * 16]     = pef[0];
    *(bf8*)&XH[row * XSTR + 128 + p * 16 + 8] = pef[1];
  }
  __syncthreads();

  int w = tid >> 6, l = tid & 63;
  int rg = w >> 2, cg = w & 3;
  int gq = l >> 4, i = l & 15;
  int col = cg * 16 + i;

  f32x4 acc[4][3];
#pragma unroll
  for (int rt = 0; rt < 4; ++rt)
#pragma unroll
    for (int t = 0; t < 3; ++t) acc[rt][t] = (f32x4){0.f, 0.f, 0.f, 0.f};

  // GEMM1: no barriers; B-tiles from global (L2-hot)
#pragma unroll
  for (int s = 0; s < 6; ++s) {
    bf8 a[4];
#pragma unroll
    for (int rt = 0; rt < 4; ++rt)
      a[rt] = *(const bf8*)&XH[(rg * 64 + rt * 16 + i) * XSTR + s * 32 + gq * 8];
#pragma unroll
    for (int t = 0; t < 3; ++t) {
      bf8 bh = *(const bf8*)(W1H + ((size_t)((cg * 3 + t) * 6 + s) * 64 + l) * 8);
#pragma unroll
      for (int rt = 0; rt < 4; ++rt) acc[rt][t] = MFMA(a[rt], bh, acc[rt][t]);
    }
  }

  // residual snapshot from staged ef (stable until H overwrite after barrier 2)
  float res[4][4];
#pragma unroll
  for (int rt = 0; rt < 4; ++rt)
#pragma unroll
    for (int r = 0; r < 4; ++r)
      res[rt][r] = (float)XH[(rg * 64 + rt * 16 + gq * 4 + r) * XSTR + 128 + col];

  float b1v[3], gv[3], bgv[3];
#pragma unroll
  for (int t = 0; t < 3; ++t) {
    int n = cg * 48 + t * 16 + i;
    b1v[t] = b1[n]; gv[t] = g[n]; bgv[t] = bg[n];
  }
#pragma unroll
  for (int rt = 0; rt < 4; ++rt)
#pragma unroll
    for (int t = 0; t < 3; ++t)
#pragma unroll
      for (int r = 0; r < 4; ++r) acc[rt][t][r] += b1v[t];

#pragma unroll
  for (int rt = 0; rt < 4; ++rt)
#pragma unroll
    for (int r = 0; r < 4; ++r) {
      float sm = 0.f, sq = 0.f;
#pragma unroll
      for (int t = 0; t < 3; ++t) { float x = acc[rt][t][r]; sm += x; sq = fmaf(x, x, sq); }
#pragma unroll
      for (int off = 1; off <= 8; off <<= 1) {
        sm += __shfl_xor(sm, off, 64);
        sq += __shfl_xor(sq, off, 64);
      }
      if (i == 0) {
        int row = rg * 64 + rt * 16 + gq * 4 + r;
        bf2 pr; pr[0] = (__bf16)sm; pr[1] = (__bf16)sq;
        *(bf2*)&Pb[row * 8 + cg * 2] = pr;
      }
    }
  __syncthreads();   // barrier 1: partials ready; all X reads (incl. res) done

  if (tid < EB) {
    bf8 pv = *(const bf8*)&Pb[tid * 8];
    float sm = (float)pv[0] + (float)pv[2] + (float)pv[4] + (float)pv[6];
    float sq = (float)pv[1] + (float)pv[3] + (float)pv[5] + (float)pv[7];
    float mean = sm * (1.f / (float)DIN);
    float var = sq * (1.f / (float)DIN) - mean * mean;
    float rstd = 1.f / sqrtf(var + 1e-5f);
    bf2 mv; mv[0] = (__bf16)mean; mv[1] = (__bf16)rstd;
    *(bf2*)&Pb[tid * 8] = mv;
  }
  __syncthreads();   // barrier 2: (mean,rstd) ready

#pragma unroll
  for (int rt = 0; rt < 4; ++rt)
#pragma unroll
    for (int r = 0; r < 4; ++r) {
      int row = rg * 64 + rt * 16 + gq * 4 + r;
      bf2 mv = *(const bf2*)&Pb[row * 8];
      float mean = (float)mv[0], rstd = (float)mv[1];
#pragma unroll
      for (int t = 0; t < 3; ++t) {
        float y = (acc[rt][t][r] - mean) * rstd * gv[t] + bgv[t];
        y = fmaxf(y, 0.f);
        XH[row * XSTR + cg * 48 + t * 16 + i] = (__bf16)y;
      }
    }
  __syncthreads();   // barrier 3: H fully published

  // GEMM2
  f32x4 acc2[4];
#pragma unroll
  for (int rt = 0; rt < 4; ++rt) acc2[rt] = (f32x4){0.f, 0.f, 0.f, 0.f};

#pragma unroll
  for (int s = 0; s < 6; ++s) {
    bf8 a2[4];
#pragma unroll
    for (int rt = 0; rt < 4; ++rt)
      a2[rt] = *(const bf8*)&XH[(rg * 64 + rt * 16 + i) * XSTR + s * 32 + gq * 8];
    bf8 bh = *(const bf8*)(W2H + ((size_t)(cg * 6 + s) * 64 + l) * 8);
#pragma unroll
    for (int rt = 0; rt < 4; ++rt) acc2[rt] = MFMA(a2[rt], bh, acc2[rt]);
  }
  __syncthreads();   // barrier 4: all H reads done; XH free for funnel

  float b2v = b2[col];
#pragma unroll
  for (int rt = 0; rt < 4; ++rt)
#pragma unroll
    for (int r = 0; r < 4; ++r) {
      int row = rg * 64 + rt * 16 + gq * 4 + r;
      XF[row * FSTR + col] = acc2[rt][r] + b2v + res[rt][r];
    }
  __syncthreads();   // barrier 5: funnel filled

  // full-line coalesced output: thread owns (row = tid>>2, q = tid&3)
  {
    int row = tid >> 2, q = tid & 3;
    const float* fr = &XF[row * FSTR + q * 16];
    if (last) {
      float* op = efout + (size_t)(e0 + row) * DD + q * 16;
#pragma unroll
      for (int k = 0; k < 4; ++k)
        *(float4*)(op + k * 4) = *(const float4*)(fr + k * 4);
    } else {
      bf8 o0, o1;
#pragma unroll
      for (int k = 0; k < 8; ++k) { o0[k] = (__bf16)fr[k]; o1[k] = (__bf16)fr[k + 8]; }
      __bf16* op = ef16 + (size_t)(e0 + row) * DD + q * 16;
      *(bf8*)op = o0;
      *(bf8*)(op + 8) = o1;
    }
  }
}

extern "C" void kernel_launch(void* const* d_in, const int* in_sizes, int n_in,
                              void* d_out, int out_size, void* d_ws, size_t ws_size,
                              hipStream_t stream) {
  const float* node_feats = (const float*)d_in[0];
  const float* edge_feats = (const float*)d_in[1];
  const int*   edge_index = (const int*)d_in[2];
  const float* conv_w  = (const float*)d_in[3];
  const float* att_src = (const float*)d_in[4];
  const float* att_dst = (const float*)d_in[5];
  const float* edge_w  = (const float*)d_in[6];
  const float* att_edge= (const float*)d_in[7];
  const float* conv_b  = (const float*)d_in[8];
  const float* ln_g    = (const float*)d_in[9];
  const float* ln_b    = (const float*)d_in[10];
  const float* up1_w   = (const float*)d_in[11];
  const float* up1_b   = (const float*)d_in[12];
  const float* up_ln_g = (const float*)d_in[13];
  const float* up_ln_b = (const float*)d_in[14];
  const float* up2_w   = (const float*)d_in[15];
  const float* up2_b   = (const float*)d_in[16];

  const int* src = edge_index;
  const int* dst = edge_index + NE;

  float* nf = (float*)d_out;
  float* efout = nf + (size_t)NN * DD;

  float* w = (float*)d_ws;
  __bf16* xh16 = (__bf16*)w; w += (size_t)NN * DD / 2;
  __bf16* nf16 = (__bf16*)w; w += (size_t)NN * DD / 2;
  __bf16* ef16 = (__bf16*)w; w += (size_t)NE * DD / 2;
  float* asrc  = w; w += (size_t)NN * NH;
  float* adst  = w; w += (size_t)NN * NH;
  float* araw  = w; w += (size_t)NE * NH;
  float* vbuf  = w; w += 4 * 256;
  __bf16* W1H  = (__bf16*)w; w += (size_t)4 * 36864 / 2;
  __bf16* W2H  = (__bf16*)w; w += (size_t)4 * 12288 / 2;
  int* deg     = (int*)w; w += NN;
  int* offs    = (int*)w; w += NN + 1;
  int* cursor  = (int*)w; w += NN;
  int* bsum    = (int*)w; w += 128;
  int* boff    = (int*)w; w += 128;
  int* csr_src = (int*)w; w += NE;
  int* posmap  = (int*)w; w += NE;

  k_init_nf<<<(NN * DD + 255) / 256, 256, 0, stream>>>(node_feats, nf);
  k_pack_w1<<<72, 256, 0, stream>>>(up1_w, W1H);
  k_pack_w2<<<24, 256, 0, stream>>>(up2_w, W2H);

  const int nb = (NN + 1023) / 1024;
  k_zero<<<(NN + 255) / 256, 256, 0, stream>>>(deg);
  k_hist<<<(NE + 255) / 256, 256, 0, stream>>>(dst, deg);
  k_scan1<<<nb, 256, 0, stream>>>(deg, offs, bsum);
  k_scan2<<<1, 64, 0, stream>>>(bsum, boff, offs, nb);
  k_scan3<<<(NN + 255) / 256, 256, 0, stream>>>(offs, boff, cursor);
  k_scatter<<<(NE + 255) / 256, 256, 0, stream>>>(src, dst, cursor, csr_src, posmap);

  k_v_all<<<4, 256, 0, stream>>>(edge_w, att_edge, vbuf);

  for (int l = 0; l < NL; ++l) {
    int last = (l == NL - 1) ? 1 : 0;
    k_xh<<<NN / 4, 256, 0, stream>>>(nf, conv_w + (size_t)l * DD * DD,
                                     att_src + (size_t)l * NH * NC,
                                     att_dst + (size_t)l * NH * NC, xh16, asrc, adst);
    if (l == 0)
      k_pass1f<<<NE / 64, 256, 0, stream>>>(edge_feats, src, dst, vbuf,
                                            asrc, adst, posmap, ef16, araw);
    else
      k_pass1b<<<NE / 64, 256, 0, stream>>>(ef16, src, dst,
                                            vbuf + (size_t)l * 256,
                                            asrc, adst, posmap, araw);
    k_gather<<<NN / 4, 256, 0, stream>>>(xh16, araw, csr_src, offs, asrc, adst,
                                         conv_b + (size_t)l * DD,
                                         ln_g + (size_t)l * DD,
                                         ln_b + (size_t)l * DD, nf, nf16);
    k_edge_mlp10<<<NE / EB, 512, 0, stream>>>(
        nf16, ef16, efout, src, dst,
        W1H + (size_t)l * 36864, up1_b + (size_t)l * DIN,
        up_ln_g + (size_t)l * DIN, up_ln_b + (size_t)l * DIN,
        W2H + (size_t)l * 12288, up2_b + (size_t)l * DD, last);
  }
}